// Round 10
// baseline (376.101 us; speedup 1.0000x reference)
//
#include <hip/hip_runtime.h>
#include <hip/hip_bf16.h>
#include <math.h>

#define SEQ 3072
#define DIM 1536
#define NH 12
#define HD 128
#define NB 24
#define BLKT 128
#define NBSQ 576          // NB*NB
#define TOPK_N 128
#define EPSV 1e-5f
#define SCALEV 0.08838834764831845f   // 1/sqrt(128)

typedef __attribute__((ext_vector_type(8))) short short8;
typedef __attribute__((ext_vector_type(4))) short short4v;
typedef __attribute__((ext_vector_type(4))) float f32x4;

typedef __attribute__((address_space(1))) void* gas1_t;
typedef __attribute__((address_space(3))) void* las3_t;

__device__ __forceinline__ float b2f(short u) {
  return __uint_as_float(((unsigned int)(unsigned short)u) << 16);
}
__device__ __forceinline__ short f2b(float x) {
  __hip_bfloat16 h = __float2bfloat16(x);
  return *reinterpret_cast<short*>(&h);
}
__device__ __forceinline__ float ldin(const void* p, size_t i, int f32) {
  return f32 ? ((const float*)p)[i] : b2f(((const short*)p)[i]);
}
// async global->LDS, 16 bytes per lane (dest linear: wave base + lane*16)
__device__ __forceinline__ void gload_lds16(const void* g, void* l) {
  __builtin_amdgcn_global_load_lds((gas1_t)g, (las3_t)l, 16, 0, 0);
}

// ---------------------------------------------------------------------------
// Detect fp32 vs bf16 inputs.
// ---------------------------------------------------------------------------
__global__ __launch_bounds__(256)
void dtype_probe(const void* __restrict__ w, int* __restrict__ flag) {
  __shared__ int cnt;
  if (threadIdx.x == 0) cnt = 0;
  __syncthreads();
  const short* p = (const short*)w;
  int local = 0;
  for (int i = threadIdx.x; i < 4096; i += 256) {
    float v = b2f(p[i]);
    if (!(fabsf(v) <= 1e3f)) local++;
  }
  atomicAdd(&cnt, local);
  __syncthreads();
  if (threadIdx.x == 0) { flag[0] = (cnt > 16) ? 1 : 0; flag[1] = 0; }
}

// ---------------------------------------------------------------------------
// Load one 8-element chunk as bf16 bits (converting from fp32 if needed).
// ---------------------------------------------------------------------------
__device__ __forceinline__ short8 ldchunk(const void* __restrict__ p, size_t idx, int f32) {
  if (f32) {
    const float* q = (const float*)p + idx;
    f32x4 a = *(const f32x4*)q;
    f32x4 b = *(const f32x4*)(q + 4);
    short8 r;
    r[0] = f2b(a[0]); r[1] = f2b(a[1]); r[2] = f2b(a[2]); r[3] = f2b(a[3]);
    r[4] = f2b(b[0]); r[5] = f2b(b[1]); r[6] = f2b(b[2]); r[7] = f2b(b[3]);
    return r;
  }
  return *(const short8*)((const short*)p + idx);
}

// ---------------------------------------------------------------------------
// Elementwise convert (or copy) input tensor -> bf16 workspace buffer.
// ---------------------------------------------------------------------------
__global__ __launch_bounds__(256)
void cvt_bf16(const void* __restrict__ in, short* __restrict__ out, int n8,
              const int* __restrict__ f) {
  int i = blockIdx.x * 256 + threadIdx.x;
  if (i >= n8) return;
  *(short8*)(out + (size_t)i * 8) = ldchunk(in, (size_t)i * 8, *f);
}

// ---------------------------------------------------------------------------
// MFMA GEMM: C = A @ W^T + bias. A bf16 [M=SEQ, K=DIM].
// 128x128 tile, BK=64, 256 thr = 4 waves (2x2), wave tile 64x64 (4x4 frags).
// LDS content is XOR-swizzled (slot c holds global chunk c^(r&7)):
//  - gload path: linear LDS dest + pre-swizzled GLOBAL chunk index (rule 21)
//  - reg path:   swizzled ds_write
// Fused-QKV: weight/bias/out selected by blockIdx.x / 12.
// ---------------------------------------------------------------------------
#define BK 64

__global__ __launch_bounds__(256)
void gemm128(const short* __restrict__ A,
             const void* __restrict__ W0, const void* __restrict__ W1, const void* __restrict__ W2,
             const void* __restrict__ b0, const void* __restrict__ b1, const void* __restrict__ b2,
             void* __restrict__ C0, void* __restrict__ C1, void* __restrict__ C2,
             int useWB, const int* __restrict__ wfp, const int* __restrict__ ofp) {
  const int fW = *wfp, fO = *ofp;
  __shared__ __attribute__((aligned(16))) short As[128 * BK];
  __shared__ __attribute__((aligned(16))) short Bs[128 * BK];
  const int tid = threadIdx.x;
  const int w = tid >> 6, lane = tid & 63;
  const int lo = lane & 15, hi = lane >> 4;
  const int wr = w >> 1, wc = w & 1;
  const int bx = blockIdx.x;
  const int wsel = bx / 12;
  const int col0 = (bx - wsel * 12) * 128;
  const int row0 = blockIdx.y * 128;
  const void* W = (wsel == 0) ? W0 : ((wsel == 1) ? W1 : W2);
  const void* bb = (wsel == 0) ? b0 : ((wsel == 1) ? b1 : b2);
  void* C = (wsel == 0) ? C0 : ((wsel == 1) ? C1 : C2);

  const f32x4 zero = {0.f, 0.f, 0.f, 0.f};
  f32x4 acc[4][4];
#pragma unroll
  for (int i = 0; i < 4; i++)
#pragma unroll
    for (int j = 0; j < 4; j++) acc[i][j] = zero;

  for (int k0 = 0; k0 < DIM; k0 += BK) {
#pragma unroll
    for (int i = 0; i < 4; i++) {
      int id = i * 256 + tid;
      int r = id >> 3, c = id & 7;
      gload_lds16(A + (size_t)(row0 + r) * DIM + k0 + (c ^ (r & 7)) * 8, &As[id * 8]);
    }
    if (useWB) {
#pragma unroll
      for (int i = 0; i < 4; i++) {
        int id = i * 256 + tid;
        int r = id >> 3, c = id & 7;
        gload_lds16((const short*)W + (size_t)(col0 + r) * DIM + k0 + (c ^ (r & 7)) * 8,
                    &Bs[id * 8]);
      }
    } else {
#pragma unroll
      for (int i = 0; i < 4; i++) {
        int id = i * 256 + tid;
        int r = id >> 3, c = id & 7;
        short8 v = ldchunk(W, (size_t)(col0 + r) * DIM + k0 + c * 8, fW);
        *(short8*)&Bs[r * BK + 8 * (c ^ (r & 7))] = v;
      }
    }
    __syncthreads();
#pragma unroll
    for (int kk = 0; kk < 2; kk++) {
      short8 av[4], bv[4];
#pragma unroll
      for (int mi = 0; mi < 4; mi++) {
        int r = wr * 64 + mi * 16 + lo;
        av[mi] = *(const short8*)&As[r * BK + 8 * ((kk * 4 + hi) ^ (r & 7))];
      }
#pragma unroll
      for (int ni = 0; ni < 4; ni++) {
        int r = wc * 64 + ni * 16 + lo;
        bv[ni] = *(const short8*)&Bs[r * BK + 8 * ((kk * 4 + hi) ^ (r & 7))];
      }
#pragma unroll
      for (int mi = 0; mi < 4; mi++)
#pragma unroll
        for (int ni = 0; ni < 4; ni++)
          acc[mi][ni] = __builtin_amdgcn_mfma_f32_16x16x32_bf16(av[mi], bv[ni], acc[mi][ni], 0, 0, 0);
    }
    __syncthreads();
  }

#pragma unroll
  for (int ni = 0; ni < 4; ni++) {
    int col = col0 + wc * 64 + ni * 16 + lo;
    float bias = ldin(bb, col, fW);
#pragma unroll
    for (int mi = 0; mi < 4; mi++) {
      int rowb = row0 + wr * 64 + mi * 16 + hi * 4;
#pragma unroll
      for (int g = 0; g < 4; g++) {
        float v = acc[mi][ni][g] + bias;
        size_t oi = (size_t)(rowb + g) * DIM + col;
        if (fO) ((float*)C)[oi] = v;
        else    ((short*)C)[oi] = f2b(v);
      }
    }
  }
}

// ---------------------------------------------------------------------------
// In-place RMSNorm + RoPE, short8-vectorized. grid = SEQ, block = 256.
// ---------------------------------------------------------------------------
__global__ __launch_bounds__(256)
void rmsnorm_rope_kernel(short* __restrict__ x, const void* __restrict__ g,
                         const void* __restrict__ cs, const void* __restrict__ sn,
                         const int* __restrict__ f) {
  const int fI = *f;
  const int s = blockIdx.x, tid = threadIdx.x;
  short* row = x + (size_t)s * DIM;
  short8 rv = {};
  float ss = 0.f;
  if (tid < 192) {
    rv = *(const short8*)(row + tid * 8);
#pragma unroll
    for (int j = 0; j < 8; j++) { float v = b2f(rv[j]); ss += v * v; }
  }
#pragma unroll
  for (int m = 32; m; m >>= 1) ss += __shfl_xor(ss, m, 64);
  __shared__ float wsum[4];
  if ((tid & 63) == 0) wsum[tid >> 6] = ss;
  __syncthreads();
  float rn = rsqrtf((wsum[0] + wsum[1] + wsum[2] + wsum[3]) * (1.0f / DIM) + EPSV);
  if (tid >= 192) return;
  short8 out;
#pragma unroll
  for (int j = 0; j < 4; j++) {
    int p = tid * 4 + j, pi = p & 63;
    float c  = ldin(cs, (size_t)s * 64 + pi, fI);
    float si = ldin(sn, (size_t)s * 64 + pi, fI);
    float xr = b2f(rv[2 * j])     * rn * ldin(g, tid * 8 + 2 * j, fI);
    float xi = b2f(rv[2 * j + 1]) * rn * ldin(g, tid * 8 + 2 * j + 1, fI);
    out[2 * j]     = f2b(xr * c - xi * si);
    out[2 * j + 1] = f2b(xr * si + xi * c);
  }
  *(short8*)(row + tid * 8) = out;
}

// ---------------------------------------------------------------------------
// Block-mean pooling. grid = (NB, DIM/256).
// ---------------------------------------------------------------------------
__global__ __launch_bounds__(256)
void pool_kernel(const short* __restrict__ x, float* __restrict__ out) {
  const int nb = blockIdx.x;
  const int d = blockIdx.y * 256 + threadIdx.x;
  float s = 0.f;
  for (int t = 0; t < BLKT; t++) s += b2f(x[(size_t)(nb * BLKT + t) * DIM + d]);
  out[nb * DIM + d] = s * (1.0f / BLKT);
}

// ---------------------------------------------------------------------------
// Draft block mask + per-task cost: pooled-QK softmax + top-128 threshold
// via bit-pattern bisection. Also emits cost[h*NB+l] = active blocks in row
// (for LPT task ordering). grid = NH.
// ---------------------------------------------------------------------------
__global__ __launch_bounds__(256)
void draft_mask_kernel(const float* __restrict__ qw, const float* __restrict__ kw,
                       int* __restrict__ bm, int* __restrict__ cost) {
  const int h = blockIdx.x, tid = threadIdx.x;
  __shared__ float qh[NB][HD];
  __shared__ float kh[NB][HD];
  __shared__ float attn[NBSQ];
  __shared__ int cw[4];

  for (int idx = tid; idx < NB * HD; idx += 256) {
    int l = idx >> 7, d = idx & 127;
    qh[l][d] = qw[l * DIM + h * HD + d];
    kh[l][d] = kw[l * DIM + h * HD + d];
  }
  __syncthreads();

  for (int idx = tid; idx < NBSQ; idx += 256) {
    int l = idx / NB, m = idx % NB;
    int rl = l >> 2, cl = l & 3, rm = m >> 2, cm = m & 3;
    bool loc = (rm >= rl - 3) && (rm <= rl + 2) && (cm >= cl - 3) && (cm <= cl + 2);
    float sc;
    if (loc) {
      sc = 0.f;
      for (int d = 0; d < HD; d++) sc += qh[l][d] * kh[m][d];
      sc *= SCALEV;
    } else {
      sc = -INFINITY;
    }
    attn[idx] = sc;
  }
  __syncthreads();

  if (tid < NB) {
    float mx = -INFINITY;
    for (int m = 0; m < NB; m++) mx = fmaxf(mx, attn[tid * NB + m]);
    float sm = 0.f;
    for (int m = 0; m < NB; m++) {
      float p = expf(attn[tid * NB + m] - mx);
      attn[tid * NB + m] = p;
      sm += p;
    }
    float inv = 1.0f / sm;
    for (int m = 0; m < NB; m++) attn[tid * NB + m] *= inv;
  }
  __syncthreads();

  unsigned int blo = 0u, bhi = 0x3F800000u;
  while (blo < bhi) {
    unsigned int mid = (blo + bhi) >> 1;
    float t = __uint_as_float(mid);
    int c = 0;
    for (int idx = tid; idx < NBSQ; idx += 256) c += (attn[idx] > t) ? 1 : 0;
#pragma unroll
    for (int m = 1; m < 64; m <<= 1) c += __shfl_xor(c, m, 64);
    if ((tid & 63) == 0) cw[tid >> 6] = c;
    __syncthreads();
    int tot = cw[0] + cw[1] + cw[2] + cw[3];
    if (tot <= TOPK_N) bhi = mid; else blo = mid + 1;
    __syncthreads();
  }
  float thr = __uint_as_float(blo);

  for (int idx = tid; idx < NBSQ; idx += 256)
    bm[h * NBSQ + idx] = (attn[idx] > thr) ? 1 : 0;

  if (tid < NB) {
    int cnt = 0;
    for (int m = 0; m < NB; m++) cnt += (attn[tid * NB + m] > thr) ? 1 : 0;
    cost[h * NB + tid] = cnt;
  }
}

// ---------------------------------------------------------------------------
// LPT task ordering: rank each XCD's 72 tasks by descending cost (tie: id).
// Task t: h = t/48, l = (t%48)>>1, half = t&1. 576 tasks, grid <<<3,256>>>.
// ---------------------------------------------------------------------------
__global__ __launch_bounds__(256)
void order_tasks(const int* __restrict__ cost, int* __restrict__ taskmap) {
  int t = blockIdx.x * 256 + threadIdx.x;
  if (t >= 576) return;
  int xcd = t / 72, base = xcd * 72;
  int h = t / 48, rem = t - h * 48, l = rem >> 1;
  int c = cost[h * NB + l];
  int rank = 0;
  for (int j = 0; j < 72; j++) {
    int tj = base + j;
    int hj = tj / 48, remj = tj - hj * 48, lj = remj >> 1;
    int cj = cost[hj * NB + lj];
    if (cj > c || (cj == c && tj < t)) rank++;
  }
  taskmap[base + rank] = t;
}

// ---------------------------------------------------------------------------
// v16 [S][DIM] -> vt [DIM][S] transpose. grid = (S/64, DIM/64), block = 256.
// ---------------------------------------------------------------------------
__global__ __launch_bounds__(256)
void transpose_kernel(const short* __restrict__ v, short* __restrict__ vt) {
  __shared__ short tile[64][68];
  const int s0 = blockIdx.x * 64, c0 = blockIdx.y * 64;
  const int tid = threadIdx.x;
#pragma unroll
  for (int i = 0; i < 4; i++) {
    int id = i * 256 + tid;
    int r = id >> 4, cq = (id & 15) * 4;
    *(short4v*)&tile[r][cq] = *(const short4v*)(v + (size_t)(s0 + r) * DIM + c0 + cq);
  }
  __syncthreads();
#pragma unroll
  for (int i = 0; i < 4; i++) {
    int id = i * 256 + tid;
    int d = id >> 4, sq = (id & 15) * 4;
    short4v val;
#pragma unroll
    for (int jj = 0; jj < 4; jj++) val[jj] = tile[sq + jj][d];
    *(short4v*)(vt + (size_t)(c0 + d) * SEQ + s0 + sq) = val;
  }
}

// ---------------------------------------------------------------------------
// Block-sparse MFMA flash attention — round 10: FINE-GRAINED TASKS + LPT.
// R9 (LDS-shared, 8-wave, 288 tasks) hit 70us, tail-limited: only 1.125
// tasks/block, cost variance 1-24 iters. Now: 576 tasks = (h, 64-row
// q-half-block), 4 waves x 256 thr, LDS 80KB -> 2 blocks/CU; per-XCD
// work-steal over 72 LPT-ordered tasks (heaviest first). Per-wave math,
// layouts, and j-order identical to R9 (verified; absmax unchanged).
// ---------------------------------------------------------------------------
__global__ __launch_bounds__(256)
void attn_mfma(const short* __restrict__ q, const short* __restrict__ k,
               const short* __restrict__ vt, const int* __restrict__ bm,
               short* __restrict__ o, int* __restrict__ ctr,
               const int* __restrict__ taskmap) {
  const int xcd = blockIdx.x & 7;
  const int tid = threadIdx.x;
  const int w = tid >> 6;               // wave 0..3 = q-tile within half-block
  const int lane = tid & 63;
  const int lo = lane & 15, hi = lane >> 4;

  __shared__ __attribute__((aligned(16))) short Ks[128 * 128];   // [tok][d]
  __shared__ __attribute__((aligned(16))) short Vs[128 * 128];   // [d][tok]
  __shared__ __attribute__((aligned(16))) short Ps[4][16 * 128];
  __shared__ int tsh;

  const f32x4 zero = {0.f, 0.f, 0.f, 0.f};
  const int sr = tid >> 4, sc = tid & 15;   // staging: rows i*16+sr, chunk sc

  for (;;) {
    if (tid == 0) tsh = atomicAdd(&ctr[xcd * 8], 1);
    __syncthreads();
    const int slot = tsh;
    if (slot >= 72) break;
    const int t = taskmap[xcd * 72 + slot];
    const int h = t / 48;
    const int rem = t - h * 48;
    const int l = rem >> 1, half = rem & 1;   // q block row l, 64-row half

    const int* bmrow = bm + h * NBSQ + l * NB;
    const short* kh = k + h * HD;
    const short* vth = vt + (size_t)h * HD * SEQ;

    const int qt = l * 8 + half * 4 + w;   // this wave's 16-row q-tile
    const int qrow = qt * 16 + lo;
    short8 qa[4];
#pragma unroll
    for (int kk = 0; kk < 4; kk++)
      qa[kk] = *(const short8*)(q + (size_t)qrow * DIM + h * HD + kk * 32 + hi * 8);

    f32x4 oacc[8];
#pragma unroll
    for (int i = 0; i < 8; i++) oacc[i] = zero;
    float m_i[4] = {-INFINITY, -INFINITY, -INFINITY, -INFINITY};
    float l_i[4] = {0.f, 0.f, 0.f, 0.f};

    // find first active j and prefetch into registers (rows i*16+sr, 8 iters)
    short8 kreg[8], vreg[8];
    int jc = 0;
    while (jc < NB && !bmrow[jc]) jc++;
    if (jc < NB) {
      const int t0 = jc * BLKT;
#pragma unroll
      for (int i = 0; i < 8; i++) {
        int r = i * 16 + sr;
        kreg[i] = *(const short8*)(kh + (size_t)(t0 + r) * DIM + sc * 8);
        vreg[i] = *(const short8*)(vth + (size_t)r * SEQ + t0 + sc * 8);
      }
    }

    while (jc < NB) {
      // commit prefetched tile to LDS (swizzled: 16B chunk slot = sc^(r&7))
#pragma unroll
      for (int i = 0; i < 8; i++) {
        int r = i * 16 + sr;
        *(short8*)&Ks[r * 128 + 8 * (sc ^ (r & 7))] = kreg[i];
        *(short8*)&Vs[r * 128 + 8 * (sc ^ (r & 7))] = vreg[i];
      }
      __syncthreads();

      // issue next active block's loads (latency hides under compute)
      int jn = jc + 1;
      while (jn < NB && !bmrow[jn]) jn++;
      if (jn < NB) {
        const int t0 = jn * BLKT;
#pragma unroll
        for (int i = 0; i < 8; i++) {
          int r = i * 16 + sr;
          kreg[i] = *(const short8*)(kh + (size_t)(t0 + r) * DIM + sc * 8);
          vreg[i] = *(const short8*)(vth + (size_t)r * SEQ + t0 + sc * 8);
        }
      }

      // QK^T: S[16 q][128 t] from LDS K
      f32x4 S[8];
#pragma unroll
      for (int tt = 0; tt < 8; tt++) {
        f32x4 s = zero;
#pragma unroll
        for (int kk = 0; kk < 4; kk++) {
          int rt = tt * 16 + lo;
          short8 kb = *(const short8*)&Ks[rt * 128 + 8 * ((kk * 4 + hi) ^ (rt & 7))];
          s = __builtin_amdgcn_mfma_f32_16x16x32_bf16(qa[kk], kb, s, 0, 0, 0);
        }
        S[tt] = s;
      }

      // online softmax per owned row r = hi*4+g (16-lane groups)
      float alpha[4];
#pragma unroll
      for (int g = 0; g < 4; g++) {
        float mx = S[0][g];
#pragma unroll
        for (int tt = 1; tt < 8; tt++) mx = fmaxf(mx, S[tt][g]);
#pragma unroll
        for (int msk = 1; msk < 16; msk <<= 1) mx = fmaxf(mx, __shfl_xor(mx, msk, 16));
        mx *= SCALEV;
        float mn = fmaxf(m_i[g], mx);
        alpha[g] = __expf(m_i[g] - mn);
        float ps = 0.f;
        int r = hi * 4 + g;
#pragma unroll
        for (int tt = 0; tt < 8; tt++) {
          float p = __expf(S[tt][g] * SCALEV - mn);
          ps += p;
          int t2 = tt * 16 + lo;
          Ps[w][r * 128 + 8 * ((t2 >> 3) ^ (r & 7)) + (t2 & 7)] = f2b(p);
        }
#pragma unroll
        for (int msk = 1; msk < 16; msk <<= 1) ps += __shfl_xor(ps, msk, 16);
        l_i[g] = l_i[g] * alpha[g] + ps;
        m_i[g] = mn;
      }
#pragma unroll
      for (int dt = 0; dt < 8; dt++) {
        f32x4 tv = oacc[dt];
        tv[0] *= alpha[0]; tv[1] *= alpha[1]; tv[2] *= alpha[2]; tv[3] *= alpha[3];
        oacc[dt] = tv;
      }

      // PV: O[16 q][128 d] += P[16][128] * V[128][128] from LDS V^T
#pragma unroll
      for (int kk = 0; kk < 4; kk++) {
        int ch = kk * 4 + hi;
        short8 pa = *(const short8*)&Ps[w][lo * 128 + 8 * (ch ^ (lo & 7))];
#pragma unroll
        for (int dt = 0; dt < 8; dt++) {
          int rd = dt * 16 + lo;
          short8 vb = *(const short8*)&Vs[rd * 128 + 8 * (ch ^ (rd & 7))];
          oacc[dt] = __builtin_amdgcn_mfma_f32_16x16x32_bf16(pa, vb, oacc[dt], 0, 0, 0);
        }
      }
      __syncthreads();
      jc = jn;
    }

    // each wave writes its own 16 q-rows (no cross-wave combine)
    float inv[4];
#pragma unroll
    for (int g = 0; g < 4; g++) inv[g] = (l_i[g] > 0.f) ? 1.f / l_i[g] : 0.f;
#pragma unroll
    for (int dt = 0; dt < 8; dt++)
#pragma unroll
      for (int g = 0; g < 4; g++)
        o[(size_t)(qt * 16 + hi * 4 + g) * DIM + h * HD + dt * 16 + lo] =
            f2b(oacc[dt][g] * inv[g]);
    __syncthreads();   // protect Ks/Vs/Ps reuse across stolen tasks
  }
}

// ---------------------------------------------------------------------------
extern "C" void kernel_launch(void* const* d_in, const int* in_sizes, int n_in,
                              void* d_out, int out_size, void* d_ws, size_t ws_size,
                              hipStream_t stream) {
  char* wsb = (char*)d_ws;
  int*   flag = (int*)(wsb + 0);                 // [0]=fp32?, [1]=0
  int*   ctr  = (int*)(wsb + 64);                // 8 XCD steal counters (stride 8 ints)
  int*   cost = (int*)(wsb + 384);               // NH*NB task costs
  int*   tmap = (int*)(wsb + 1536);              // 576 LPT-ordered task ids
  float* qw   = (float*)(wsb + 4096);            // NB*DIM fp32
  float* kw   = (float*)(wsb + 4096 + 147456);
  int*   bm   = (int*)(wsb + 4096 + 294912);     // NH*NBSQ int
  const size_t base = 327680;
  short* q16 = (short*)(wsb + base);             // bf16 bits, SEQ*DIM each
  short* k16 = q16 + (size_t)SEQ * DIM;
  short* v16 = k16 + (size_t)SEQ * DIM;
  short* xb  = v16 + (size_t)SEQ * DIM;          // bf16 x; dead after QKV gemm
  short* vt  = xb;                               // alias: [DIM][SEQ] V^T
  short* o16 = v16;                              // alias: attn out

  const int bigws = (ws_size >= (size_t)56 * 1024 * 1024) ? 1 : 0;
  short* wqb = xb + (size_t)SEQ * DIM;           // bf16 weights (bigws only)
  short* wkb = wqb + (size_t)DIM * DIM;
  short* wvb = wkb + (size_t)DIM * DIM;
  short* wob = wqb;                              // reuse wqb slot after QKV

  dtype_probe<<<1, 256, 0, stream>>>(d_in[1], flag);
  hipMemsetAsync(ctr, 0, 256, stream);

  const int n8x = SEQ * DIM / 8;                 // 589824
  const int n8w = DIM * DIM / 8;                 // 294912
  cvt_bf16<<<n8x / 256, 256, 0, stream>>>(d_in[0], xb, n8x, flag);
  if (bigws) {
    cvt_bf16<<<n8w / 256, 256, 0, stream>>>(d_in[1], wqb, n8w, flag);
    cvt_bf16<<<n8w / 256, 256, 0, stream>>>(d_in[3], wkb, n8w, flag);
    cvt_bf16<<<n8w / 256, 256, 0, stream>>>(d_in[5], wvb, n8w, flag);
  }

  // fused QKV GEMM: N_total = 3*DIM, grid (36, 24)
  gemm128<<<dim3(36, SEQ / 128), 256, 0, stream>>>(
      xb,
      bigws ? (const void*)wqb : d_in[1],
      bigws ? (const void*)wkb : d_in[3],
      bigws ? (const void*)wvb : d_in[5],
      d_in[2], d_in[4], d_in[6],
      q16, k16, v16,
      bigws, flag, flag + 1);

  rmsnorm_rope_kernel<<<SEQ, 256, 0, stream>>>(q16, d_in[9],  d_in[11], d_in[12], flag);
  rmsnorm_rope_kernel<<<SEQ, 256, 0, stream>>>(k16, d_in[10], d_in[11], d_in[12], flag);

  pool_kernel<<<dim3(NB, DIM / 256), 256, 0, stream>>>(q16, qw);
  pool_kernel<<<dim3(NB, DIM / 256), 256, 0, stream>>>(k16, kw);

  draft_mask_kernel<<<NH, 256, 0, stream>>>(qw, kw, bm, cost);
  order_tasks<<<3, 256, 0, stream>>>(cost, tmap);

  transpose_kernel<<<dim3(SEQ / 64, DIM / 64), 256, 0, stream>>>(v16, vt);
  if (bigws) cvt_bf16<<<n8w / 256, 256, 0, stream>>>(d_in[7], wob, n8w, flag);

  // persistent LDS-shared attention: 512 blocks (2/CU, 4 waves), per-XCD
  // steal over 72 LPT-ordered tasks each
  attn_mfma<<<512, 256, 0, stream>>>(q16, k16, vt, bm, o16, ctr, tmap);

  // output GEMM: N = DIM, grid (12, 24)
  gemm128<<<dim3(12, SEQ / 128), 256, 0, stream>>>(
      o16,
      bigws ? (const void*)wob : d_in[7], bigws ? (const void*)wob : d_in[7],
      bigws ? (const void*)wob : d_in[7],
      d_in[8], d_in[8], d_in[8],
      d_out, d_out, d_out,
      bigws, flag, flag);
}

// Round 12
// 354.295 us; speedup vs baseline: 1.0615x; 1.0615x over previous
//
#include <hip/hip_runtime.h>
#include <hip/hip_bf16.h>
#include <math.h>

#define SEQ 3072
#define DIM 1536
#define NH 12
#define HD 128
#define NB 24
#define BLKT 128
#define NBSQ 576          // NB*NB
#define TOPK_N 128
#define EPSV 1e-5f
#define SCALEV 0.08838834764831845f   // 1/sqrt(128)

typedef __attribute__((ext_vector_type(8))) short short8;
typedef __attribute__((ext_vector_type(4))) short short4v;
typedef __attribute__((ext_vector_type(4))) float f32x4;

typedef __attribute__((address_space(1))) void* gas1_t;
typedef __attribute__((address_space(3))) void* las3_t;

__device__ __forceinline__ float b2f(short u) {
  return __uint_as_float(((unsigned int)(unsigned short)u) << 16);
}
__device__ __forceinline__ short f2b(float x) {
  __hip_bfloat16 h = __float2bfloat16(x);
  return *reinterpret_cast<short*>(&h);
}
__device__ __forceinline__ float ldin(const void* p, size_t i, int f32) {
  return f32 ? ((const float*)p)[i] : b2f(((const short*)p)[i]);
}
// async global->LDS, 16 bytes per lane (dest linear: wave base + lane*16)
__device__ __forceinline__ void gload_lds16(const void* g, void* l) {
  __builtin_amdgcn_global_load_lds((gas1_t)g, (las3_t)l, 16, 0, 0);
}

// ---------------------------------------------------------------------------
// Detect fp32 vs bf16 inputs.
// ---------------------------------------------------------------------------
__global__ __launch_bounds__(256)
void dtype_probe(const void* __restrict__ w, int* __restrict__ flag) {
  __shared__ int cnt;
  if (threadIdx.x == 0) cnt = 0;
  __syncthreads();
  const short* p = (const short*)w;
  int local = 0;
  for (int i = threadIdx.x; i < 4096; i += 256) {
    float v = b2f(p[i]);
    if (!(fabsf(v) <= 1e3f)) local++;
  }
  atomicAdd(&cnt, local);
  __syncthreads();
  if (threadIdx.x == 0) { flag[0] = (cnt > 16) ? 1 : 0; flag[1] = 0; }
}

// ---------------------------------------------------------------------------
// Load one 8-element chunk as bf16 bits (converting from fp32 if needed).
// ---------------------------------------------------------------------------
__device__ __forceinline__ short8 ldchunk(const void* __restrict__ p, size_t idx, int f32) {
  if (f32) {
    const float* q = (const float*)p + idx;
    f32x4 a = *(const f32x4*)q;
    f32x4 b = *(const f32x4*)(q + 4);
    short8 r;
    r[0] = f2b(a[0]); r[1] = f2b(a[1]); r[2] = f2b(a[2]); r[3] = f2b(a[3]);
    r[4] = f2b(b[0]); r[5] = f2b(b[1]); r[6] = f2b(b[2]); r[7] = f2b(b[3]);
    return r;
  }
  return *(const short8*)((const short*)p + idx);
}

// ---------------------------------------------------------------------------
// Elementwise convert (or copy) input tensor -> bf16 workspace buffer.
// ---------------------------------------------------------------------------
__global__ __launch_bounds__(256)
void cvt_bf16(const void* __restrict__ in, short* __restrict__ out, int n8,
              const int* __restrict__ f) {
  int i = blockIdx.x * 256 + threadIdx.x;
  if (i >= n8) return;
  *(short8*)(out + (size_t)i * 8) = ldchunk(in, (size_t)i * 8, *f);
}

// Fused 3-tensor weight convert (blockIdx.y selects tensor).
__global__ __launch_bounds__(256)
void cvt_bf16_w(const void* __restrict__ i0, const void* __restrict__ i1,
                const void* __restrict__ i2, short* __restrict__ o0,
                short* __restrict__ o1, short* __restrict__ o2, int n8,
                const int* __restrict__ f) {
  const void* in = (blockIdx.y == 0) ? i0 : ((blockIdx.y == 1) ? i1 : i2);
  short* out = (blockIdx.y == 0) ? o0 : ((blockIdx.y == 1) ? o1 : o2);
  int i = blockIdx.x * 256 + threadIdx.x;
  if (i >= n8) return;
  *(short8*)(out + (size_t)i * 8) = ldchunk(in, (size_t)i * 8, *f);
}

// ---------------------------------------------------------------------------
// MFMA GEMM: C = A @ W^T + bias. A bf16 [M=SEQ, K=DIM].
// 128x128 tile, BK=64, 256 thr = 4 waves (2x2), wave tile 64x64 (4x4 frags).
// LDS XOR-swizzled (slot c holds global chunk c^(r&7)); gload path uses
// pre-swizzled GLOBAL chunk index + linear LDS dest (rule 21).
// Fused-QKV: weight/bias/out selected by blockIdx.x / 12.
// vtr: if nonzero, wsel==2 output is written TRANSPOSED to C2[col][row]
// (direct V^T materialization; values bit-identical to transpose-after).
// ---------------------------------------------------------------------------
#define BK 64

__global__ __launch_bounds__(256)
void gemm128(const short* __restrict__ A,
             const void* __restrict__ W0, const void* __restrict__ W1, const void* __restrict__ W2,
             const void* __restrict__ b0, const void* __restrict__ b1, const void* __restrict__ b2,
             void* __restrict__ C0, void* __restrict__ C1, void* __restrict__ C2,
             int useWB, const int* __restrict__ wfp, const int* __restrict__ ofp,
             int vtr) {
  const int fW = *wfp, fO = *ofp;
  __shared__ __attribute__((aligned(16))) short As[128 * BK];
  __shared__ __attribute__((aligned(16))) short Bs[128 * BK];
  const int tid = threadIdx.x;
  const int w = tid >> 6, lane = tid & 63;
  const int lo = lane & 15, hi = lane >> 4;
  const int wr = w >> 1, wc = w & 1;
  const int bx = blockIdx.x;
  const int wsel = bx / 12;
  const int col0 = (bx - wsel * 12) * 128;
  const int row0 = blockIdx.y * 128;
  const void* W = (wsel == 0) ? W0 : ((wsel == 1) ? W1 : W2);
  const void* bb = (wsel == 0) ? b0 : ((wsel == 1) ? b1 : b2);
  void* C = (wsel == 0) ? C0 : ((wsel == 1) ? C1 : C2);

  const f32x4 zero = {0.f, 0.f, 0.f, 0.f};
  f32x4 acc[4][4];
#pragma unroll
  for (int i = 0; i < 4; i++)
#pragma unroll
    for (int j = 0; j < 4; j++) acc[i][j] = zero;

  for (int k0 = 0; k0 < DIM; k0 += BK) {
#pragma unroll
    for (int i = 0; i < 4; i++) {
      int id = i * 256 + tid;
      int r = id >> 3, c = id & 7;
      gload_lds16(A + (size_t)(row0 + r) * DIM + k0 + (c ^ (r & 7)) * 8, &As[id * 8]);
    }
    if (useWB) {
#pragma unroll
      for (int i = 0; i < 4; i++) {
        int id = i * 256 + tid;
        int r = id >> 3, c = id & 7;
        gload_lds16((const short*)W + (size_t)(col0 + r) * DIM + k0 + (c ^ (r & 7)) * 8,
                    &Bs[id * 8]);
      }
    } else {
#pragma unroll
      for (int i = 0; i < 4; i++) {
        int id = i * 256 + tid;
        int r = id >> 3, c = id & 7;
        short8 v = ldchunk(W, (size_t)(col0 + r) * DIM + k0 + c * 8, fW);
        *(short8*)&Bs[r * BK + 8 * (c ^ (r & 7))] = v;
      }
    }
    __syncthreads();
#pragma unroll
    for (int kk = 0; kk < 2; kk++) {
      short8 av[4], bv[4];
#pragma unroll
      for (int mi = 0; mi < 4; mi++) {
        int r = wr * 64 + mi * 16 + lo;
        av[mi] = *(const short8*)&As[r * BK + 8 * ((kk * 4 + hi) ^ (r & 7))];
      }
#pragma unroll
      for (int ni = 0; ni < 4; ni++) {
        int r = wc * 64 + ni * 16 + lo;
        bv[ni] = *(const short8*)&Bs[r * BK + 8 * ((kk * 4 + hi) ^ (r & 7))];
      }
#pragma unroll
      for (int mi = 0; mi < 4; mi++)
#pragma unroll
        for (int ni = 0; ni < 4; ni++)
          acc[mi][ni] = __builtin_amdgcn_mfma_f32_16x16x32_bf16(av[mi], bv[ni], acc[mi][ni], 0, 0, 0);
    }
    __syncthreads();
  }

  if (vtr && wsel == 2) {
    // transposed write: C2 is vt[DIM][SEQ]; 4 consecutive rows -> one 8B store
    short* vtC = (short*)C;
#pragma unroll
    for (int ni = 0; ni < 4; ni++) {
      int col = col0 + wc * 64 + ni * 16 + lo;
      float bias = ldin(bb, col, fW);
#pragma unroll
      for (int mi = 0; mi < 4; mi++) {
        int rowb = row0 + wr * 64 + mi * 16 + hi * 4;
        short4v pk;
#pragma unroll
        for (int g = 0; g < 4; g++) pk[g] = f2b(acc[mi][ni][g] + bias);
        *(short4v*)(vtC + (size_t)col * SEQ + rowb) = pk;
      }
    }
    return;
  }

#pragma unroll
  for (int ni = 0; ni < 4; ni++) {
    int col = col0 + wc * 64 + ni * 16 + lo;
    float bias = ldin(bb, col, fW);
#pragma unroll
    for (int mi = 0; mi < 4; mi++) {
      int rowb = row0 + wr * 64 + mi * 16 + hi * 4;
#pragma unroll
      for (int g = 0; g < 4; g++) {
        float v = acc[mi][ni][g] + bias;
        size_t oi = (size_t)(rowb + g) * DIM + col;
        if (fO) ((float*)C)[oi] = v;
        else    ((short*)C)[oi] = f2b(v);
      }
    }
  }
}

// ---------------------------------------------------------------------------
// In-place RMSNorm + RoPE for q AND k (blockIdx.y selects). grid = (SEQ, 2).
// ---------------------------------------------------------------------------
__global__ __launch_bounds__(256)
void rmsnorm_rope2(short* __restrict__ qx, short* __restrict__ kx,
                   const void* __restrict__ gq, const void* __restrict__ gk,
                   const void* __restrict__ cs, const void* __restrict__ sn,
                   const int* __restrict__ f) {
  const int fI = *f;
  short* x = blockIdx.y ? kx : qx;
  const void* g = blockIdx.y ? gk : gq;
  const int s = blockIdx.x, tid = threadIdx.x;
  short* row = x + (size_t)s * DIM;
  short8 rv = {};
  float ss = 0.f;
  if (tid < 192) {
    rv = *(const short8*)(row + tid * 8);
#pragma unroll
    for (int j = 0; j < 8; j++) { float v = b2f(rv[j]); ss += v * v; }
  }
#pragma unroll
  for (int m = 32; m; m >>= 1) ss += __shfl_xor(ss, m, 64);
  __shared__ float wsum[4];
  if ((tid & 63) == 0) wsum[tid >> 6] = ss;
  __syncthreads();
  float rn = rsqrtf((wsum[0] + wsum[1] + wsum[2] + wsum[3]) * (1.0f / DIM) + EPSV);
  if (tid >= 192) return;
  short8 out;
#pragma unroll
  for (int j = 0; j < 4; j++) {
    int p = tid * 4 + j, pi = p & 63;
    float c  = ldin(cs, (size_t)s * 64 + pi, fI);
    float si = ldin(sn, (size_t)s * 64 + pi, fI);
    float xr = b2f(rv[2 * j])     * rn * ldin(g, tid * 8 + 2 * j, fI);
    float xi = b2f(rv[2 * j + 1]) * rn * ldin(g, tid * 8 + 2 * j + 1, fI);
    out[2 * j]     = f2b(xr * c - xi * si);
    out[2 * j + 1] = f2b(xr * si + xi * c);
  }
  *(short8*)(row + tid * 8) = out;
}

// ---------------------------------------------------------------------------
// Block-mean pooling for q AND k. grid = (NB, DIM/256, 2).
// ---------------------------------------------------------------------------
__global__ __launch_bounds__(256)
void pool2(const short* __restrict__ qx, const short* __restrict__ kx,
           float* __restrict__ qw, float* __restrict__ kw) {
  const short* x = blockIdx.z ? kx : qx;
  float* out = blockIdx.z ? kw : qw;
  const int nb = blockIdx.x;
  const int d = blockIdx.y * 256 + threadIdx.x;
  float s = 0.f;
  for (int t = 0; t < BLKT; t++) s += b2f(x[(size_t)(nb * BLKT + t) * DIM + d]);
  out[nb * DIM + d] = s * (1.0f / BLKT);
}

// ---------------------------------------------------------------------------
// Draft block mask + per-task cost. Top-128 threshold via ONE-PASS exact
// rank select: for each present value v, rank(v) = #{u > v}; thr =
// min{v : rank(v) <= 128} == the 129th-largest value with multiplicity
// (provably identical to the previous bisection's result). grid = NH.
// ---------------------------------------------------------------------------
__global__ __launch_bounds__(256)
void draft_mask_kernel(const float* __restrict__ qw, const float* __restrict__ kw,
                       int* __restrict__ bm, int* __restrict__ cost) {
  const int h = blockIdx.x, tid = threadIdx.x;
  __shared__ float qh[NB][HD];
  __shared__ float kh[NB][HD];
  __shared__ float attn[NBSQ];
  __shared__ float mw[4];

  for (int idx = tid; idx < NB * HD; idx += 256) {
    int l = idx >> 7, d = idx & 127;
    qh[l][d] = qw[l * DIM + h * HD + d];
    kh[l][d] = kw[l * DIM + h * HD + d];
  }
  __syncthreads();

  for (int idx = tid; idx < NBSQ; idx += 256) {
    int l = idx / NB, m = idx % NB;
    int rl = l >> 2, cl = l & 3, rm = m >> 2, cm = m & 3;
    bool loc = (rm >= rl - 3) && (rm <= rl + 2) && (cm >= cl - 3) && (cm <= cl + 2);
    float sc;
    if (loc) {
      sc = 0.f;
      for (int d = 0; d < HD; d++) sc += qh[l][d] * kh[m][d];
      sc *= SCALEV;
    } else {
      sc = -INFINITY;
    }
    attn[idx] = sc;
  }
  __syncthreads();

  if (tid < NB) {
    float mx = -INFINITY;
    for (int m = 0; m < NB; m++) mx = fmaxf(mx, attn[tid * NB + m]);
    float sm = 0.f;
    for (int m = 0; m < NB; m++) {
      float p = expf(attn[tid * NB + m] - mx);
      attn[tid * NB + m] = p;
      sm += p;
    }
    float inv = 1.0f / sm;
    for (int m = 0; m < NB; m++) attn[tid * NB + m] *= inv;
  }
  __syncthreads();

  // one-pass exact selection of the 129th-largest (with multiplicity)
  float best = INFINITY;
  for (int base = tid; base < NBSQ; base += 256) {
    float v = attn[base];
    int cnt = 0;
    for (int j = 0; j < NBSQ; j++) cnt += (attn[j] > v) ? 1 : 0;
    if (cnt <= TOPK_N) best = fminf(best, v);
  }
#pragma unroll
  for (int m = 1; m < 64; m <<= 1) best = fminf(best, __shfl_xor(best, m, 64));
  if ((tid & 63) == 0) mw[tid >> 6] = best;
  __syncthreads();
  float thr = fminf(fminf(mw[0], mw[1]), fminf(mw[2], mw[3]));

  for (int idx = tid; idx < NBSQ; idx += 256)
    bm[h * NBSQ + idx] = (attn[idx] > thr) ? 1 : 0;

  if (tid < NB) {
    int cnt = 0;
    for (int m = 0; m < NB; m++) cnt += (attn[tid * NB + m] > thr) ? 1 : 0;
    cost[h * NB + tid] = cnt;
  }
}

// ---------------------------------------------------------------------------
// LPT task ordering: rank each XCD's 72 tasks by descending cost (tie: id).
// Task t: h = t/48, l = (t%48)>>1, half = t&1. 576 tasks, grid <<<3,256>>>.
// ---------------------------------------------------------------------------
__global__ __launch_bounds__(256)
void order_tasks(const int* __restrict__ cost, int* __restrict__ taskmap) {
  int t = blockIdx.x * 256 + threadIdx.x;
  if (t >= 576) return;
  int xcd = t / 72, base = xcd * 72;
  int h = t / 48, rem = t - h * 48, l = rem >> 1;
  int c = cost[h * NB + l];
  int rank = 0;
  for (int j = 0; j < 72; j++) {
    int tj = base + j;
    int hj = tj / 48, remj = tj - hj * 48, lj = remj >> 1;
    int cj = cost[hj * NB + lj];
    if (cj > c || (cj == c && tj < t)) rank++;
  }
  taskmap[base + rank] = t;
}

// ---------------------------------------------------------------------------
// Block-sparse MFMA flash attention — round 12: R10-verified body (separate
// wave-private Ps, 2 barriers/tile) with LDS trimmed to EXACTLY 80 KiB:
// Ks 32K + Vs 32K + Ps 16K = 81920 B -> 2 blocks/CU (R10 was 82432 -> 1).
// The steal-slot word is unioned into Ps[0][0..1]: it is consumed into a
// register right after the post-atomic barrier, and the first P write is
// separated from that read by the commit barrier; P is dead between tasks
// (task-end barrier precedes the next atomic). R11's Ks-alias experiment
// (crash suspect) is reverted. 576 LPT tasks, per-XCD steal, T14 prefetch.
// ---------------------------------------------------------------------------
__global__ __launch_bounds__(256)
void attn_mfma(const short* __restrict__ q, const short* __restrict__ k,
               const short* __restrict__ vt, const int* __restrict__ bm,
               short* __restrict__ o, int* __restrict__ ctr,
               const int* __restrict__ taskmap) {
  const int xcd = blockIdx.x & 7;
  const int tid = threadIdx.x;
  const int w = tid >> 6;               // wave 0..3 = q-tile within half-block
  const int lane = tid & 63;
  const int lo = lane & 15, hi = lane >> 4;

  __shared__ __attribute__((aligned(16))) short Ks[128 * 128];   // [tok][d]
  __shared__ __attribute__((aligned(16))) short Vs[128 * 128];   // [d][tok]
  __shared__ __attribute__((aligned(16))) short Ps[4][2048];     // wave-private P; word0 = steal slot

  int* tshp = (int*)&Ps[0][0];
  short* Pw = Ps[w];

  const f32x4 zero = {0.f, 0.f, 0.f, 0.f};
  const int sr = tid >> 4, sc = tid & 15;   // staging: rows i*16+sr, chunk sc

  for (;;) {
    if (tid == 0) *tshp = atomicAdd(&ctr[xcd * 8], 1);
    __syncthreads();
    const int slot = *tshp;
    if (slot >= 72) break;
    const int t = taskmap[xcd * 72 + slot];
    const int h = t / 48;
    const int rem = t - h * 48;
    const int l = rem >> 1, half = rem & 1;   // q block row l, 64-row half

    const int* bmrow = bm + h * NBSQ + l * NB;
    const short* kh = k + h * HD;
    const short* vth = vt + (size_t)h * HD * SEQ;

    const int qt = l * 8 + half * 4 + w;   // this wave's 16-row q-tile
    const int qrow = qt * 16 + lo;
    short8 qa[4];
#pragma unroll
    for (int kk = 0; kk < 4; kk++)
      qa[kk] = *(const short8*)(q + (size_t)qrow * DIM + h * HD + kk * 32 + hi * 8);

    f32x4 oacc[8];
#pragma unroll
    for (int i = 0; i < 8; i++) oacc[i] = zero;
    float m_i[4] = {-INFINITY, -INFINITY, -INFINITY, -INFINITY};
    float l_i[4] = {0.f, 0.f, 0.f, 0.f};

    // find first active j and prefetch into registers (rows i*16+sr, 8 iters)
    short8 kreg[8], vreg[8];
    int jc = 0;
    while (jc < NB && !bmrow[jc]) jc++;
    if (jc < NB) {
      const int t0 = jc * BLKT;
#pragma unroll
      for (int i = 0; i < 8; i++) {
        int r = i * 16 + sr;
        kreg[i] = *(const short8*)(kh + (size_t)(t0 + r) * DIM + sc * 8);
        vreg[i] = *(const short8*)(vth + (size_t)r * SEQ + t0 + sc * 8);
      }
    }

    while (jc < NB) {
      // commit prefetched tile to LDS (swizzled: 16B chunk slot = sc^(r&7))
#pragma unroll
      for (int i = 0; i < 8; i++) {
        int r = i * 16 + sr;
        *(short8*)&Ks[r * 128 + 8 * (sc ^ (r & 7))] = kreg[i];
        *(short8*)&Vs[r * 128 + 8 * (sc ^ (r & 7))] = vreg[i];
      }
      __syncthreads();

      // issue next active block's loads (latency hides under compute)
      int jn = jc + 1;
      while (jn < NB && !bmrow[jn]) jn++;
      if (jn < NB) {
        const int t0 = jn * BLKT;
#pragma unroll
        for (int i = 0; i < 8; i++) {
          int r = i * 16 + sr;
          kreg[i] = *(const short8*)(kh + (size_t)(t0 + r) * DIM + sc * 8);
          vreg[i] = *(const short8*)(vth + (size_t)r * SEQ + t0 + sc * 8);
        }
      }

      // QK^T: S[16 q][128 t] from LDS K
      f32x4 S[8];
#pragma unroll
      for (int tt = 0; tt < 8; tt++) {
        f32x4 s = zero;
#pragma unroll
        for (int kk = 0; kk < 4; kk++) {
          int rt = tt * 16 + lo;
          short8 kb = *(const short8*)&Ks[rt * 128 + 8 * ((kk * 4 + hi) ^ (rt & 7))];
          s = __builtin_amdgcn_mfma_f32_16x16x32_bf16(qa[kk], kb, s, 0, 0, 0);
        }
        S[tt] = s;
      }

      // online softmax per owned row r = hi*4+g (16-lane groups)
      float alpha[4];
#pragma unroll
      for (int g = 0; g < 4; g++) {
        float mx = S[0][g];
#pragma unroll
        for (int tt = 1; tt < 8; tt++) mx = fmaxf(mx, S[tt][g]);
#pragma unroll
        for (int msk = 1; msk < 16; msk <<= 1) mx = fmaxf(mx, __shfl_xor(mx, msk, 16));
        mx *= SCALEV;
        float mn = fmaxf(m_i[g], mx);
        alpha[g] = __expf(m_i[g] - mn);
        float ps = 0.f;
        int r = hi * 4 + g;
#pragma unroll
        for (int tt = 0; tt < 8; tt++) {
          float p = __expf(S[tt][g] * SCALEV - mn);
          ps += p;
          int t2 = tt * 16 + lo;
          Pw[r * 128 + 8 * ((t2 >> 3) ^ (r & 7)) + (t2 & 7)] = f2b(p);
        }
#pragma unroll
        for (int msk = 1; msk < 16; msk <<= 1) ps += __shfl_xor(ps, msk, 16);
        l_i[g] = l_i[g] * alpha[g] + ps;
        m_i[g] = mn;
      }
#pragma unroll
      for (int dt = 0; dt < 8; dt++) {
        f32x4 tv = oacc[dt];
        tv[0] *= alpha[0]; tv[1] *= alpha[1]; tv[2] *= alpha[2]; tv[3] *= alpha[3];
        oacc[dt] = tv;
      }

      // PV: O[16 q][128 d] += P[16][128] * V[128][128] from LDS V^T
#pragma unroll
      for (int kk = 0; kk < 4; kk++) {
        int ch = kk * 4 + hi;
        short8 pa = *(const short8*)&Pw[lo * 128 + 8 * (ch ^ (lo & 7))];
#pragma unroll
        for (int dt = 0; dt < 8; dt++) {
          int rd = dt * 16 + lo;
          short8 vb = *(const short8*)&Vs[rd * 128 + 8 * (ch ^ (rd & 7))];
          oacc[dt] = __builtin_amdgcn_mfma_f32_16x16x32_bf16(pa, vb, oacc[dt], 0, 0, 0);
        }
      }
      __syncthreads();
      jc = jn;
    }

    // each wave writes its own 16 q-rows (no cross-wave combine)
    float inv[4];
#pragma unroll
    for (int g = 0; g < 4; g++) inv[g] = (l_i[g] > 0.f) ? 1.f / l_i[g] : 0.f;
#pragma unroll
    for (int dt = 0; dt < 8; dt++)
#pragma unroll
      for (int g = 0; g < 4; g++)
        o[(size_t)(qt * 16 + hi * 4 + g) * DIM + h * HD + dt * 16 + lo] =
            f2b(oacc[dt][g] * inv[g]);
    __syncthreads();   // protect Ks/Vs/Ps reuse across stolen tasks
  }
}

// ---------------------------------------------------------------------------
extern "C" void kernel_launch(void* const* d_in, const int* in_sizes, int n_in,
                              void* d_out, int out_size, void* d_ws, size_t ws_size,
                              hipStream_t stream) {
  char* wsb = (char*)d_ws;
  int*   flag = (int*)(wsb + 0);                 // [0]=fp32?, [1]=0
  int*   ctr  = (int*)(wsb + 64);                // 8 XCD steal counters (stride 8 ints)
  int*   cost = (int*)(wsb + 384);               // NH*NB task costs
  int*   tmap = (int*)(wsb + 1536);              // 576 LPT-ordered task ids
  float* qw   = (float*)(wsb + 4096);            // NB*DIM fp32
  float* kw   = (float*)(wsb + 4096 + 147456);
  int*   bm   = (int*)(wsb + 4096 + 294912);     // NH*NBSQ int
  const size_t base = 327680;
  short* q16 = (short*)(wsb + base);             // bf16 bits, SEQ*DIM each
  short* k16 = q16 + (size_t)SEQ * DIM;
  short* vt  = k16 + (size_t)SEQ * DIM;          // [DIM][SEQ] V^T (written by gemm)
  short* xb  = vt + (size_t)SEQ * DIM;           // bf16 x; dead after QKV gemm
  short* o16 = xb;                               // attn out reuses xb

  const int bigws = (ws_size >= (size_t)56 * 1024 * 1024) ? 1 : 0;
  short* wqb = xb + (size_t)SEQ * DIM;           // bf16 weights (bigws only)
  short* wkb = wqb + (size_t)DIM * DIM;
  short* wvb = wkb + (size_t)DIM * DIM;
  short* wob = wqb;                              // reuse wqb slot after QKV

  dtype_probe<<<1, 256, 0, stream>>>(d_in[1], flag);
  hipMemsetAsync(ctr, 0, 256, stream);

  const int n8x = SEQ * DIM / 8;                 // 589824
  const int n8w = DIM * DIM / 8;                 // 294912
  cvt_bf16<<<n8x / 256, 256, 0, stream>>>(d_in[0], xb, n8x, flag);
  if (bigws) {
    cvt_bf16_w<<<dim3(n8w / 256, 3), 256, 0, stream>>>(
        d_in[1], d_in[3], d_in[5], wqb, wkb, wvb, n8w, flag);
  }

  // fused QKV GEMM: N_total = 3*DIM, grid (36, 24); V written transposed
  gemm128<<<dim3(36, SEQ / 128), 256, 0, stream>>>(
      xb,
      bigws ? (const void*)wqb : d_in[1],
      bigws ? (const void*)wkb : d_in[3],
      bigws ? (const void*)wvb : d_in[5],
      d_in[2], d_in[4], d_in[6],
      q16, k16, vt,
      bigws, flag, flag + 1, /*vtr=*/1);

  rmsnorm_rope2<<<dim3(SEQ, 2), 256, 0, stream>>>(q16, k16, d_in[9], d_in[10],
                                                  d_in[11], d_in[12], flag);

  pool2<<<dim3(NB, DIM / 256, 2), 256, 0, stream>>>(q16, k16, qw, kw);

  draft_mask_kernel<<<NH, 256, 0, stream>>>(qw, kw, bm, cost);
  order_tasks<<<3, 256, 0, stream>>>(cost, tmap);

  if (bigws) cvt_bf16<<<n8w / 256, 256, 0, stream>>>(d_in[7], wob, n8w, flag);

  // persistent LDS-shared attention: 512 blocks (2/CU, 4 waves), per-XCD
  // steal over 72 LPT-ordered tasks each
  attn_mfma<<<512, 256, 0, stream>>>(q16, k16, vt, bm, o16, ctr, tmap);

  // output GEMM: N = DIM, grid (12, 24)
  gemm128<<<dim3(12, SEQ / 128), 256, 0, stream>>>(
      o16,
      bigws ? (const void*)wob : d_in[7], bigws ? (const void*)wob : d_in[7],
      bigws ? (const void*)wob : d_in[7],
      d_in[8], d_in[8], d_in[8],
      d_out, d_out, d_out,
      bigws, flag, flag, /*vtr=*/0);
}

// Round 13
// 334.477 us; speedup vs baseline: 1.1244x; 1.0593x over previous
//
#include <hip/hip_runtime.h>
#include <hip/hip_bf16.h>
#include <math.h>

#define SEQ 3072
#define DIM 1536
#define NH 12
#define HD 128
#define NB 24
#define BLKT 128
#define NBSQ 576          // NB*NB
#define TOPK_N 128
#define EPSV 1e-5f
#define SCALEV 0.08838834764831845f   // 1/sqrt(128)

typedef __attribute__((ext_vector_type(8))) short short8;
typedef __attribute__((ext_vector_type(4))) short short4v;
typedef __attribute__((ext_vector_type(4))) float f32x4;

typedef __attribute__((address_space(1))) void* gas1_t;
typedef __attribute__((address_space(3))) void* las3_t;

__device__ __forceinline__ float b2f(short u) {
  return __uint_as_float(((unsigned int)(unsigned short)u) << 16);
}
__device__ __forceinline__ short f2b(float x) {
  __hip_bfloat16 h = __float2bfloat16(x);
  return *reinterpret_cast<short*>(&h);
}
__device__ __forceinline__ float ldin(const void* p, size_t i, int f32) {
  return f32 ? ((const float*)p)[i] : b2f(((const short*)p)[i]);
}
// async global->LDS, 16 bytes per lane (dest linear: wave base + lane*16)
__device__ __forceinline__ void gload_lds16(const void* g, void* l) {
  __builtin_amdgcn_global_load_lds((gas1_t)g, (las3_t)l, 16, 0, 0);
}

// ---------------------------------------------------------------------------
// Detect fp32 vs bf16 inputs; also zeroes the 64-int steal-counter array
// (folds the former hipMemsetAsync launch).
// ---------------------------------------------------------------------------
__global__ __launch_bounds__(256)
void dtype_probe(const void* __restrict__ w, int* __restrict__ flag,
                 int* __restrict__ ctr) {
  __shared__ int cnt;
  if (threadIdx.x == 0) cnt = 0;
  if (threadIdx.x < 64) ctr[threadIdx.x] = 0;
  __syncthreads();
  const short* p = (const short*)w;
  int local = 0;
  for (int i = threadIdx.x; i < 4096; i += 256) {
    float v = b2f(p[i]);
    if (!(fabsf(v) <= 1e3f)) local++;
  }
  atomicAdd(&cnt, local);
  __syncthreads();
  if (threadIdx.x == 0) { flag[0] = (cnt > 16) ? 1 : 0; flag[1] = 0; }
}

// ---------------------------------------------------------------------------
// Load one 8-element chunk as bf16 bits (converting from fp32 if needed).
// ---------------------------------------------------------------------------
__device__ __forceinline__ short8 ldchunk(const void* __restrict__ p, size_t idx, int f32) {
  if (f32) {
    const float* q = (const float*)p + idx;
    f32x4 a = *(const f32x4*)q;
    f32x4 b = *(const f32x4*)(q + 4);
    short8 r;
    r[0] = f2b(a[0]); r[1] = f2b(a[1]); r[2] = f2b(a[2]); r[3] = f2b(a[3]);
    r[4] = f2b(b[0]); r[5] = f2b(b[1]); r[6] = f2b(b[2]); r[7] = f2b(b[3]);
    return r;
  }
  return *(const short8*)((const short*)p + idx);
}

// ---------------------------------------------------------------------------
// Fused convert: ALL input tensors -> bf16 workspace in ONE launch.
// blockIdx.y: 0 = x (n8x chunks), 1..4 = wq/wk/wv/wo (n8w chunks each).
// When weights are not converted (small ws), launch with gridDim.y = 1.
// ---------------------------------------------------------------------------
__global__ __launch_bounds__(256)
void cvt_all(const void* __restrict__ ix, const void* __restrict__ iq,
             const void* __restrict__ ik, const void* __restrict__ iv,
             const void* __restrict__ io,
             short* __restrict__ ox, short* __restrict__ oq,
             short* __restrict__ ok, short* __restrict__ ov,
             short* __restrict__ oo,
             int n8x, int n8w, const int* __restrict__ f) {
  const int y = blockIdx.y;
  const void* in = (y == 0) ? ix : ((y == 1) ? iq : ((y == 2) ? ik : ((y == 3) ? iv : io)));
  short* out = (y == 0) ? ox : ((y == 1) ? oq : ((y == 2) ? ok : ((y == 3) ? ov : oo)));
  const int n8 = (y == 0) ? n8x : n8w;
  int i = blockIdx.x * 256 + threadIdx.x;
  if (i >= n8) return;
  *(short8*)(out + (size_t)i * 8) = ldchunk(in, (size_t)i * 8, *f);
}

// ---------------------------------------------------------------------------
// MFMA GEMM: C = A @ W^T + bias. A bf16 [M=SEQ, K=DIM].
// 128x128 tile, BK=64, 256 thr = 4 waves (2x2), wave tile 64x64 (4x4 frags).
// LDS XOR-swizzled (slot c holds global chunk c^(r&7)); gload path uses
// pre-swizzled GLOBAL chunk index + linear LDS dest (rule 21).
// Fused-QKV: weight/bias/out selected by blockIdx.x / 12.
// vtr: if nonzero, wsel==2 output is written TRANSPOSED to C2[col][row].
// ---------------------------------------------------------------------------
#define BK 64

__global__ __launch_bounds__(256)
void gemm128(const short* __restrict__ A,
             const void* __restrict__ W0, const void* __restrict__ W1, const void* __restrict__ W2,
             const void* __restrict__ b0, const void* __restrict__ b1, const void* __restrict__ b2,
             void* __restrict__ C0, void* __restrict__ C1, void* __restrict__ C2,
             int useWB, const int* __restrict__ wfp, const int* __restrict__ ofp,
             int vtr) {
  const int fW = *wfp, fO = *ofp;
  __shared__ __attribute__((aligned(16))) short As[128 * BK];
  __shared__ __attribute__((aligned(16))) short Bs[128 * BK];
  const int tid = threadIdx.x;
  const int w = tid >> 6, lane = tid & 63;
  const int lo = lane & 15, hi = lane >> 4;
  const int wr = w >> 1, wc = w & 1;
  const int bx = blockIdx.x;
  const int wsel = bx / 12;
  const int col0 = (bx - wsel * 12) * 128;
  const int row0 = blockIdx.y * 128;
  const void* W = (wsel == 0) ? W0 : ((wsel == 1) ? W1 : W2);
  const void* bb = (wsel == 0) ? b0 : ((wsel == 1) ? b1 : b2);
  void* C = (wsel == 0) ? C0 : ((wsel == 1) ? C1 : C2);

  const f32x4 zero = {0.f, 0.f, 0.f, 0.f};
  f32x4 acc[4][4];
#pragma unroll
  for (int i = 0; i < 4; i++)
#pragma unroll
    for (int j = 0; j < 4; j++) acc[i][j] = zero;

  for (int k0 = 0; k0 < DIM; k0 += BK) {
#pragma unroll
    for (int i = 0; i < 4; i++) {
      int id = i * 256 + tid;
      int r = id >> 3, c = id & 7;
      gload_lds16(A + (size_t)(row0 + r) * DIM + k0 + (c ^ (r & 7)) * 8, &As[id * 8]);
    }
    if (useWB) {
#pragma unroll
      for (int i = 0; i < 4; i++) {
        int id = i * 256 + tid;
        int r = id >> 3, c = id & 7;
        gload_lds16((const short*)W + (size_t)(col0 + r) * DIM + k0 + (c ^ (r & 7)) * 8,
                    &Bs[id * 8]);
      }
    } else {
#pragma unroll
      for (int i = 0; i < 4; i++) {
        int id = i * 256 + tid;
        int r = id >> 3, c = id & 7;
        short8 v = ldchunk(W, (size_t)(col0 + r) * DIM + k0 + c * 8, fW);
        *(short8*)&Bs[r * BK + 8 * (c ^ (r & 7))] = v;
      }
    }
    __syncthreads();
#pragma unroll
    for (int kk = 0; kk < 2; kk++) {
      short8 av[4], bv[4];
#pragma unroll
      for (int mi = 0; mi < 4; mi++) {
        int r = wr * 64 + mi * 16 + lo;
        av[mi] = *(const short8*)&As[r * BK + 8 * ((kk * 4 + hi) ^ (r & 7))];
      }
#pragma unroll
      for (int ni = 0; ni < 4; ni++) {
        int r = wc * 64 + ni * 16 + lo;
        bv[ni] = *(const short8*)&Bs[r * BK + 8 * ((kk * 4 + hi) ^ (r & 7))];
      }
#pragma unroll
      for (int mi = 0; mi < 4; mi++)
#pragma unroll
        for (int ni = 0; ni < 4; ni++)
          acc[mi][ni] = __builtin_amdgcn_mfma_f32_16x16x32_bf16(av[mi], bv[ni], acc[mi][ni], 0, 0, 0);
    }
    __syncthreads();
  }

  if (vtr && wsel == 2) {
    short* vtC = (short*)C;
#pragma unroll
    for (int ni = 0; ni < 4; ni++) {
      int col = col0 + wc * 64 + ni * 16 + lo;
      float bias = ldin(bb, col, fW);
#pragma unroll
      for (int mi = 0; mi < 4; mi++) {
        int rowb = row0 + wr * 64 + mi * 16 + hi * 4;
        short4v pk;
#pragma unroll
        for (int g = 0; g < 4; g++) pk[g] = f2b(acc[mi][ni][g] + bias);
        *(short4v*)(vtC + (size_t)col * SEQ + rowb) = pk;
      }
    }
    return;
  }

#pragma unroll
  for (int ni = 0; ni < 4; ni++) {
    int col = col0 + wc * 64 + ni * 16 + lo;
    float bias = ldin(bb, col, fW);
#pragma unroll
    for (int mi = 0; mi < 4; mi++) {
      int rowb = row0 + wr * 64 + mi * 16 + hi * 4;
#pragma unroll
      for (int g = 0; g < 4; g++) {
        float v = acc[mi][ni][g] + bias;
        size_t oi = (size_t)(rowb + g) * DIM + col;
        if (fO) ((float*)C)[oi] = v;
        else    ((short*)C)[oi] = f2b(v);
      }
    }
  }
}

// ---------------------------------------------------------------------------
// In-place RMSNorm + RoPE for q AND k (blockIdx.y selects). grid = (SEQ, 2).
// ---------------------------------------------------------------------------
__global__ __launch_bounds__(256)
void rmsnorm_rope2(short* __restrict__ qx, short* __restrict__ kx,
                   const void* __restrict__ gq, const void* __restrict__ gk,
                   const void* __restrict__ cs, const void* __restrict__ sn,
                   const int* __restrict__ f) {
  const int fI = *f;
  short* x = blockIdx.y ? kx : qx;
  const void* g = blockIdx.y ? gk : gq;
  const int s = blockIdx.x, tid = threadIdx.x;
  short* row = x + (size_t)s * DIM;
  short8 rv = {};
  float ss = 0.f;
  if (tid < 192) {
    rv = *(const short8*)(row + tid * 8);
#pragma unroll
    for (int j = 0; j < 8; j++) { float v = b2f(rv[j]); ss += v * v; }
  }
#pragma unroll
  for (int m = 32; m; m >>= 1) ss += __shfl_xor(ss, m, 64);
  __shared__ float wsum[4];
  if ((tid & 63) == 0) wsum[tid >> 6] = ss;
  __syncthreads();
  float rn = rsqrtf((wsum[0] + wsum[1] + wsum[2] + wsum[3]) * (1.0f / DIM) + EPSV);
  if (tid >= 192) return;
  short8 out;
#pragma unroll
  for (int j = 0; j < 4; j++) {
    int p = tid * 4 + j, pi = p & 63;
    float c  = ldin(cs, (size_t)s * 64 + pi, fI);
    float si = ldin(sn, (size_t)s * 64 + pi, fI);
    float xr = b2f(rv[2 * j])     * rn * ldin(g, tid * 8 + 2 * j, fI);
    float xi = b2f(rv[2 * j + 1]) * rn * ldin(g, tid * 8 + 2 * j + 1, fI);
    out[2 * j]     = f2b(xr * c - xi * si);
    out[2 * j + 1] = f2b(xr * si + xi * c);
  }
  *(short8*)(row + tid * 8) = out;
}

// ---------------------------------------------------------------------------
// Block-mean pooling for q AND k. grid = (NB, DIM/256, 2).
// ---------------------------------------------------------------------------
__global__ __launch_bounds__(256)
void pool2(const short* __restrict__ qx, const short* __restrict__ kx,
           float* __restrict__ qw, float* __restrict__ kw) {
  const short* x = blockIdx.z ? kx : qx;
  float* out = blockIdx.z ? kw : qw;
  const int nb = blockIdx.x;
  const int d = blockIdx.y * 256 + threadIdx.x;
  float s = 0.f;
  for (int t = 0; t < BLKT; t++) s += b2f(x[(size_t)(nb * BLKT + t) * DIM + d]);
  out[nb * DIM + d] = s * (1.0f / BLKT);
}

// ---------------------------------------------------------------------------
// Draft block mask + per-task cost — 1024 threads (was 256; this kernel is
// 12 blocks on 256 CUs, pure critical-path latency). Top-128 threshold via
// one-pass exact rank select; thr is a pure min-reduction so the result is
// bit-identical at any thread count. grid = NH, block = 1024.
// ---------------------------------------------------------------------------
__global__ __launch_bounds__(1024)
void draft_mask_kernel(const float* __restrict__ qw, const float* __restrict__ kw,
                       int* __restrict__ bm, int* __restrict__ cost) {
  const int h = blockIdx.x, tid = threadIdx.x;
  __shared__ float qh[NB][HD];
  __shared__ float kh[NB][HD];
  __shared__ float attn[NBSQ];
  __shared__ float mw[16];

  for (int idx = tid; idx < NB * HD; idx += 1024) {
    int l = idx >> 7, d = idx & 127;
    qh[l][d] = qw[l * DIM + h * HD + d];
    kh[l][d] = kw[l * DIM + h * HD + d];
  }
  __syncthreads();

  for (int idx = tid; idx < NBSQ; idx += 1024) {
    int l = idx / NB, m = idx % NB;
    int rl = l >> 2, cl = l & 3, rm = m >> 2, cm = m & 3;
    bool loc = (rm >= rl - 3) && (rm <= rl + 2) && (cm >= cl - 3) && (cm <= cl + 2);
    float sc;
    if (loc) {
      sc = 0.f;
      for (int d = 0; d < HD; d++) sc += qh[l][d] * kh[m][d];
      sc *= SCALEV;
    } else {
      sc = -INFINITY;
    }
    attn[idx] = sc;
  }
  __syncthreads();

  if (tid < NB) {
    float mx = -INFINITY;
    for (int m = 0; m < NB; m++) mx = fmaxf(mx, attn[tid * NB + m]);
    float sm = 0.f;
    for (int m = 0; m < NB; m++) {
      float p = expf(attn[tid * NB + m] - mx);
      attn[tid * NB + m] = p;
      sm += p;
    }
    float inv = 1.0f / sm;
    for (int m = 0; m < NB; m++) attn[tid * NB + m] *= inv;
  }
  __syncthreads();

  // one-pass exact selection of the 129th-largest (with multiplicity)
  float best = INFINITY;
  for (int base = tid; base < NBSQ; base += 1024) {
    float v = attn[base];
    int cnt = 0;
    for (int j = 0; j < NBSQ; j++) cnt += (attn[j] > v) ? 1 : 0;
    if (cnt <= TOPK_N) best = fminf(best, v);
  }
#pragma unroll
  for (int m = 1; m < 64; m <<= 1) best = fminf(best, __shfl_xor(best, m, 64));
  if ((tid & 63) == 0) mw[tid >> 6] = best;
  __syncthreads();
  float thr = INFINITY;
#pragma unroll
  for (int i = 0; i < 16; i++) thr = fminf(thr, mw[i]);

  for (int idx = tid; idx < NBSQ; idx += 1024)
    bm[h * NBSQ + idx] = (attn[idx] > thr) ? 1 : 0;

  if (tid < NB) {
    int cnt = 0;
    for (int m = 0; m < NB; m++) cnt += (attn[tid * NB + m] > thr) ? 1 : 0;
    cost[h * NB + tid] = cnt;
  }
}

// ---------------------------------------------------------------------------
// LPT task ordering: rank each XCD's 72 tasks by descending cost (tie: id).
// Task t: h = t/48, l = (t%48)>>1, half = t&1. 576 tasks, grid <<<3,256>>>.
// ---------------------------------------------------------------------------
__global__ __launch_bounds__(256)
void order_tasks(const int* __restrict__ cost, int* __restrict__ taskmap) {
  int t = blockIdx.x * 256 + threadIdx.x;
  if (t >= 576) return;
  int xcd = t / 72, base = xcd * 72;
  int h = t / 48, rem = t - h * 48, l = rem >> 1;
  int c = cost[h * NB + l];
  int rank = 0;
  for (int j = 0; j < 72; j++) {
    int tj = base + j;
    int hj = tj / 48, remj = tj - hj * 48, lj = remj >> 1;
    int cj = cost[hj * NB + lj];
    if (cj > c || (cj == c && tj < t)) rank++;
  }
  taskmap[base + rank] = t;
}

// ---------------------------------------------------------------------------
// Block-sparse MFMA flash attention — R12-verified: 576 LPT tasks, per-XCD
// work-steal, LDS-shared K/V across 4 q-tiles, wave-private Ps; LDS exactly
// 80 KiB (Ks 32K + Vs 32K + Ps 16K) -> 2 blocks/CU. Steal-slot word lives
// in Ps[0][0..1] (task-scoped; separated from P writes by commit barrier).
// ---------------------------------------------------------------------------
__global__ __launch_bounds__(256)
void attn_mfma(const short* __restrict__ q, const short* __restrict__ k,
               const short* __restrict__ vt, const int* __restrict__ bm,
               short* __restrict__ o, int* __restrict__ ctr,
               const int* __restrict__ taskmap) {
  const int xcd = blockIdx.x & 7;
  const int tid = threadIdx.x;
  const int w = tid >> 6;               // wave 0..3 = q-tile within half-block
  const int lane = tid & 63;
  const int lo = lane & 15, hi = lane >> 4;

  __shared__ __attribute__((aligned(16))) short Ks[128 * 128];   // [tok][d]
  __shared__ __attribute__((aligned(16))) short Vs[128 * 128];   // [d][tok]
  __shared__ __attribute__((aligned(16))) short Ps[4][2048];     // wave-private P; word0 = steal slot

  int* tshp = (int*)&Ps[0][0];
  short* Pw = Ps[w];

  const f32x4 zero = {0.f, 0.f, 0.f, 0.f};
  const int sr = tid >> 4, sc = tid & 15;   // staging: rows i*16+sr, chunk sc

  for (;;) {
    if (tid == 0) *tshp = atomicAdd(&ctr[xcd * 8], 1);
    __syncthreads();
    const int slot = *tshp;
    if (slot >= 72) break;
    const int t = taskmap[xcd * 72 + slot];
    const int h = t / 48;
    const int rem = t - h * 48;
    const int l = rem >> 1, half = rem & 1;   // q block row l, 64-row half

    const int* bmrow = bm + h * NBSQ + l * NB;
    const short* kh = k + h * HD;
    const short* vth = vt + (size_t)h * HD * SEQ;

    const int qt = l * 8 + half * 4 + w;   // this wave's 16-row q-tile
    const int qrow = qt * 16 + lo;
    short8 qa[4];
#pragma unroll
    for (int kk = 0; kk < 4; kk++)
      qa[kk] = *(const short8*)(q + (size_t)qrow * DIM + h * HD + kk * 32 + hi * 8);

    f32x4 oacc[8];
#pragma unroll
    for (int i = 0; i < 8; i++) oacc[i] = zero;
    float m_i[4] = {-INFINITY, -INFINITY, -INFINITY, -INFINITY};
    float l_i[4] = {0.f, 0.f, 0.f, 0.f};

    // find first active j and prefetch into registers (rows i*16+sr, 8 iters)
    short8 kreg[8], vreg[8];
    int jc = 0;
    while (jc < NB && !bmrow[jc]) jc++;
    if (jc < NB) {
      const int t0 = jc * BLKT;
#pragma unroll
      for (int i = 0; i < 8; i++) {
        int r = i * 16 + sr;
        kreg[i] = *(const short8*)(kh + (size_t)(t0 + r) * DIM + sc * 8);
        vreg[i] = *(const short8*)(vth + (size_t)r * SEQ + t0 + sc * 8);
      }
    }

    while (jc < NB) {
      // commit prefetched tile to LDS (swizzled: 16B chunk slot = sc^(r&7))
#pragma unroll
      for (int i = 0; i < 8; i++) {
        int r = i * 16 + sr;
        *(short8*)&Ks[r * 128 + 8 * (sc ^ (r & 7))] = kreg[i];
        *(short8*)&Vs[r * 128 + 8 * (sc ^ (r & 7))] = vreg[i];
      }
      __syncthreads();

      // issue next active block's loads (latency hides under compute)
      int jn = jc + 1;
      while (jn < NB && !bmrow[jn]) jn++;
      if (jn < NB) {
        const int t0 = jn * BLKT;
#pragma unroll
        for (int i = 0; i < 8; i++) {
          int r = i * 16 + sr;
          kreg[i] = *(const short8*)(kh + (size_t)(t0 + r) * DIM + sc * 8);
          vreg[i] = *(const short8*)(vth + (size_t)r * SEQ + t0 + sc * 8);
        }
      }

      // QK^T: S[16 q][128 t] from LDS K
      f32x4 S[8];
#pragma unroll
      for (int tt = 0; tt < 8; tt++) {
        f32x4 s = zero;
#pragma unroll
        for (int kk = 0; kk < 4; kk++) {
          int rt = tt * 16 + lo;
          short8 kb = *(const short8*)&Ks[rt * 128 + 8 * ((kk * 4 + hi) ^ (rt & 7))];
          s = __builtin_amdgcn_mfma_f32_16x16x32_bf16(qa[kk], kb, s, 0, 0, 0);
        }
        S[tt] = s;
      }

      // online softmax per owned row r = hi*4+g (16-lane groups)
      float alpha[4];
#pragma unroll
      for (int g = 0; g < 4; g++) {
        float mx = S[0][g];
#pragma unroll
        for (int tt = 1; tt < 8; tt++) mx = fmaxf(mx, S[tt][g]);
#pragma unroll
        for (int msk = 1; msk < 16; msk <<= 1) mx = fmaxf(mx, __shfl_xor(mx, msk, 16));
        mx *= SCALEV;
        float mn = fmaxf(m_i[g], mx);
        alpha[g] = __expf(m_i[g] - mn);
        float ps = 0.f;
        int r = hi * 4 + g;
#pragma unroll
        for (int tt = 0; tt < 8; tt++) {
          float p = __expf(S[tt][g] * SCALEV - mn);
          ps += p;
          int t2 = tt * 16 + lo;
          Pw[r * 128 + 8 * ((t2 >> 3) ^ (r & 7)) + (t2 & 7)] = f2b(p);
        }
#pragma unroll
        for (int msk = 1; msk < 16; msk <<= 1) ps += __shfl_xor(ps, msk, 16);
        l_i[g] = l_i[g] * alpha[g] + ps;
        m_i[g] = mn;
      }
#pragma unroll
      for (int dt = 0; dt < 8; dt++) {
        f32x4 tv = oacc[dt];
        tv[0] *= alpha[0]; tv[1] *= alpha[1]; tv[2] *= alpha[2]; tv[3] *= alpha[3];
        oacc[dt] = tv;
      }

      // PV: O[16 q][128 d] += P[16][128] * V[128][128] from LDS V^T
#pragma unroll
      for (int kk = 0; kk < 4; kk++) {
        int ch = kk * 4 + hi;
        short8 pa = *(const short8*)&Pw[lo * 128 + 8 * (ch ^ (lo & 7))];
#pragma unroll
        for (int dt = 0; dt < 8; dt++) {
          int rd = dt * 16 + lo;
          short8 vb = *(const short8*)&Vs[rd * 128 + 8 * (ch ^ (rd & 7))];
          oacc[dt] = __builtin_amdgcn_mfma_f32_16x16x32_bf16(pa, vb, oacc[dt], 0, 0, 0);
        }
      }
      __syncthreads();
      jc = jn;
    }

    // each wave writes its own 16 q-rows (no cross-wave combine)
    float inv[4];
#pragma unroll
    for (int g = 0; g < 4; g++) inv[g] = (l_i[g] > 0.f) ? 1.f / l_i[g] : 0.f;
#pragma unroll
    for (int dt = 0; dt < 8; dt++)
#pragma unroll
      for (int g = 0; g < 4; g++)
        o[(size_t)(qt * 16 + hi * 4 + g) * DIM + h * HD + dt * 16 + lo] =
            f2b(oacc[dt][g] * inv[g]);
    __syncthreads();   // protect Ks/Vs/Ps reuse across stolen tasks
  }
}

// ---------------------------------------------------------------------------
extern "C" void kernel_launch(void* const* d_in, const int* in_sizes, int n_in,
                              void* d_out, int out_size, void* d_ws, size_t ws_size,
                              hipStream_t stream) {
  char* wsb = (char*)d_ws;
  int*   flag = (int*)(wsb + 0);                 // [0]=fp32?, [1]=0
  int*   ctr  = (int*)(wsb + 64);                // 8 XCD steal counters (stride 8 ints)
  int*   cost = (int*)(wsb + 384);               // NH*NB task costs
  int*   tmap = (int*)(wsb + 1536);              // 576 LPT-ordered task ids
  float* qw   = (float*)(wsb + 4096);            // NB*DIM fp32
  float* kw   = (float*)(wsb + 4096 + 147456);
  int*   bm   = (int*)(wsb + 4096 + 294912);     // NH*NBSQ int
  const size_t base = 327680;
  short* q16 = (short*)(wsb + base);             // bf16 bits, SEQ*DIM each
  short* k16 = q16 + (size_t)SEQ * DIM;
  short* vt  = k16 + (size_t)SEQ * DIM;          // [DIM][SEQ] V^T (written by gemm)
  short* xb  = vt + (size_t)SEQ * DIM;           // bf16 x; dead after QKV gemm
  short* o16 = xb;                               // attn out reuses xb

  const int bigws = (ws_size >= (size_t)56 * 1024 * 1024) ? 1 : 0;
  short* wqb = xb + (size_t)SEQ * DIM;           // bf16 weights (bigws only)
  short* wkb = wqb + (size_t)DIM * DIM;
  short* wvb = wkb + (size_t)DIM * DIM;
  short* wob = wvb + (size_t)DIM * DIM;          // wo gets its own slot now

  dtype_probe<<<1, 256, 0, stream>>>(d_in[1], flag, ctr);

  const int n8x = SEQ * DIM / 8;                 // 589824
  const int n8w = DIM * DIM / 8;                 // 294912
  // one fused convert launch: x (+ all 4 weights when bigws)
  cvt_all<<<dim3(n8x / 256, bigws ? 5 : 1), 256, 0, stream>>>(
      d_in[0], d_in[1], d_in[3], d_in[5], d_in[7],
      xb, wqb, wkb, wvb, wob, n8x, n8w, flag);

  // fused QKV GEMM: N_total = 3*DIM, grid (36, 24); V written transposed
  gemm128<<<dim3(36, SEQ / 128), 256, 0, stream>>>(
      xb,
      bigws ? (const void*)wqb : d_in[1],
      bigws ? (const void*)wkb : d_in[3],
      bigws ? (const void*)wvb : d_in[5],
      d_in[2], d_in[4], d_in[6],
      q16, k16, vt,
      bigws, flag, flag + 1, /*vtr=*/1);

  rmsnorm_rope2<<<dim3(SEQ, 2), 256, 0, stream>>>(q16, k16, d_in[9], d_in[10],
                                                  d_in[11], d_in[12], flag);

  pool2<<<dim3(NB, DIM / 256, 2), 256, 0, stream>>>(q16, k16, qw, kw);

  draft_mask_kernel<<<NH, 1024, 0, stream>>>(qw, kw, bm, cost);
  order_tasks<<<3, 256, 0, stream>>>(cost, tmap);

  // persistent LDS-shared attention: 512 blocks (2/CU, 4 waves), per-XCD
  // steal over 72 LPT-ordered tasks each
  attn_mfma<<<512, 256, 0, stream>>>(q16, k16, vt, bm, o16, ctr, tmap);

  // output GEMM: N = DIM, grid (12, 24)
  gemm128<<<dim3(12, SEQ / 128), 256, 0, stream>>>(
      o16,
      bigws ? (const void*)wob : d_in[7], bigws ? (const void*)wob : d_in[7],
      bigws ? (const void*)wob : d_in[7],
      d_in[8], d_in[8], d_in[8],
      d_out, d_out, d_out,
      bigws, flag, flag, /*vtr=*/0);
}